// Round 21
// baseline (62.399 us; speedup 1.0000x reference)
//
#include <hip/hip_runtime.h>
#include <hip/hip_bf16.h>

// B=8192 rows, N=64 nodes, C=256. Per node: MLP 1->C->C->1 on s=Q*Y, then
// softmax over [z0, z_1..z_64]. Output f32 [B, 65].
//
// Round 21: R20 exact interval compaction + COALESCED build outputs.
//  - entries stream-compacted per (n,strip): count walk -> block scan ->
//    write walk (contiguous ascending). u16 offset table for eval.
//  - AccP/offs staged in LDS, written coalesced (strip-major).
//  - eval: z = A*s+B + sum over entries[off[I]..off[I+1]) per strip.

typedef unsigned int u32;
#define CAP 8224   // exact bound: 257 intervals x 32 d per strip

// sum across each 16-lane DPP row; every lane gets the row total
__device__ __forceinline__ float row_reduce16(float x) {
    int v;
    v = __builtin_amdgcn_update_dpp(0, __float_as_int(x), 0xB1, 0xF, 0xF, false);
    x += __int_as_float(v);
    v = __builtin_amdgcn_update_dpp(0, __float_as_int(x), 0x4E, 0xF, 0xF, false);
    x += __int_as_float(v);
    v = __builtin_amdgcn_update_dpp(0, __float_as_int(x), 0x124, 0xF, 0xF, false);
    x += __int_as_float(v);
    v = __builtin_amdgcn_update_dpp(0, __float_as_int(x), 0x128, 0xF, 0xF, false);
    x += __int_as_float(v);
    return x;
}

// ---------------------------------------------------------------------------
// K1: prep. blocks 0..127: S[n][b] = Q[b][n]*Y[b][n] (64x64 LDS transpose).
//           blocks 128..191: knee s*_k = -b1_k/w1_k + bitonic sort.
// ---------------------------------------------------------------------------
__global__ __launch_bounds__(256) void prep(
    const float* __restrict__ Q, const float* __restrict__ Y,
    const float* __restrict__ W1, const float* __restrict__ b1,
    float* __restrict__ S, float* __restrict__ knots, int* __restrict__ perm)
{
    __shared__ float ts[64][65];
    __shared__ float key[256];
    __shared__ int   idx[256];

    const int blk = blockIdx.x;
    const int tid = threadIdx.x;

    if (blk < 128) {
        const int b0 = blk << 6;
        #pragma unroll
        for (int jj = 0; jj < 16; jj++) {
            int i = tid + (jj << 8);
            int r = i >> 6, c = i & 63;
            ts[r][c] = Q[(size_t)(b0 + r) * 64 + c] * Y[(size_t)(b0 + r) * 64 + c];
        }
        __syncthreads();
        #pragma unroll
        for (int jj = 0; jj < 16; jj++) {
            int i = tid + (jj << 8);
            int nn = i >> 6, bb = i & 63;
            S[((size_t)nn << 13) + b0 + bb] = ts[bb][nn];
        }
    } else {
        const int n = blk - 128;
        {
            float w = W1[n * 256 + tid];
            float b = b1[n * 256 + tid];
            key[tid] = -b / w;
            idx[tid] = tid;
        }
        __syncthreads();
        for (int k = 2; k <= 256; k <<= 1) {
            for (int j = k >> 1; j > 0; j >>= 1) {
                int p = tid ^ j;
                if (p > tid) {
                    float a = key[tid], c = key[p];
                    bool up = ((tid & k) == 0);
                    if (up ? (a > c) : (a < c)) {
                        int ia = idx[tid];
                        key[tid] = c; idx[tid] = idx[p];
                        key[p] = a; idx[p] = ia;
                    }
                }
                __syncthreads();
            }
        }
        knots[n * 256 + tid] = key[tid];
        perm[n * 256 + tid]  = idx[tid];
    }
}

// ---------------------------------------------------------------------------
// K2: build_sort.
// blocks 0..511: scan + classify + compact; (n = blk>>3, strip = blk&7).
// blocks 512..767: sort one (node, quarter) of samples by interval.
// ---------------------------------------------------------------------------
__global__ __launch_bounds__(256) void build_sort(
    const float* __restrict__ W1, const float* __restrict__ b1,
    const float* __restrict__ W2, const float* __restrict__ b2,
    const float* __restrict__ W3, const int* __restrict__ perm,
    const float* __restrict__ S, const float* __restrict__ knots,
    float4* __restrict__ entries, float2* __restrict__ AccP,
    unsigned short* __restrict__ offs, uint2* __restrict__ sorted)
{
    __shared__ float  w1s[256], b1s[256], kns[256];
    __shared__ int    pm[256];
    __shared__ float  part[16][16][8];
    __shared__ float2 accL[257];
    __shared__ u32    cntU[258];

    const int blk = blockIdx.x;
    const int tid = threadIdx.x;
    const int lane = tid & 63;

    if (blk < 512) {
        // ================= scan+classify+compact role =================
        const int n    = blk >> 3;
        const int strip= blk & 7;
        const int prl  = tid & 15;
        const int seg  = tid >> 4;
        const int prg  = (strip << 4) + prl;
        const int d0   = prg << 1;
        const int g    = (n << 3) + strip;          // strip-major group id

        w1s[tid] = W1[n * 256 + tid];
        b1s[tid] = b1[n * 256 + tid];
        kns[tid] = knots[n * 256 + tid];
        pm[tid]  = perm[n * 256 + tid];
        __syncthreads();

        const float w30 = W3[n * 256 + d0];
        const float w31 = W3[n * 256 + d0 + 1];
        const float* W2n = W2 + ((size_t)n << 16);
        float4* estream = entries + (size_t)g * CAP;
        float2 vreg[16];

        // ---- phase 1: per-segment partials (cache W2 in regs) ----
        {
            float ba0 = 0.f, bc0 = 0.f, ba1 = 0.f, bc1 = 0.f;
            float da0 = 0.f, dc0 = 0.f, da1 = 0.f, dc1 = 0.f;
            #pragma unroll
            for (int i = 0; i < 16; ++i) {
                int   kj = pm[(seg << 4) + i];
                float w  = w1s[kj];
                float bb = b1s[kj];
                float2 v = *reinterpret_cast<const float2*>(&W2n[kj * 256 + d0]);
                vreg[i] = v;
                if (w < 0.f) {
                    ba0 = fmaf(v.x, w, ba0); bc0 = fmaf(v.x, bb, bc0);
                    ba1 = fmaf(v.y, w, ba1); bc1 = fmaf(v.y, bb, bc1);
                }
                float aw = fabsf(w);
                float cs = (w > 0.f) ? bb : -bb;
                da0 = fmaf(v.x, aw, da0); dc0 = fmaf(v.x, cs, dc0);
                da1 = fmaf(v.y, aw, da1); dc1 = fmaf(v.y, cs, dc1);
            }
            float* p = part[seg][prl];
            p[0] = ba0; p[1] = bc0; p[2] = ba1; p[3] = bc1;
            p[4] = da0; p[5] = dc0; p[6] = da1; p[7] = dc1;
        }
        __syncthreads();

        // ---- phase 2 (16 threads): base totals, classify I=0 (entries at
        //      stream offset 0 + excl), seed per-segment start values ----
        if (tid < 16) {
            const int pr = tid;
            float sa0 = 0.f, sc0 = 0.f, sa1 = 0.f, sc1 = 0.f;
            #pragma unroll
            for (int sg = 0; sg < 16; ++sg) {
                const float* p = part[sg][pr];
                sa0 += p[0]; sc0 += p[1]; sa1 += p[2]; sc1 += p[3];
            }
            const int dd = ((strip << 4) + pr) << 1;
            sc0 += b2[n * 256 + dd];
            sc1 += b2[n * 256 + dd + 1];

            float k0 = kns[0];
            float hLo0 = (sa0 != 0.f) ? -sa0 : sc0;
            float hHi0 = fmaf(sa0, k0, sc0);
            float hLo1 = (sa1 != 0.f) ? -sa1 : sc1;
            float hHi1 = fmaf(sa1, k0, sc1);
            bool act0 = hLo0 > 0.f && hHi0 > 0.f, drp0 = hLo0 <= 0.f && hHi0 <= 0.f;
            bool act1 = hLo1 > 0.f && hHi1 > 0.f, drp1 = hLo1 <= 0.f && hHi1 <= 0.f;
            bool cr0 = !act0 && !drp0, cr1 = !act1 && !drp1;
            float As = (act0 ? w30 * sa0 : 0.f) + (act1 ? w31 * sa1 : 0.f);
            float Bs = (act0 ? w30 * sc0 : 0.f) + (act1 ? w31 * sc1 : 0.f);
            As = row_reduce16(As); Bs = row_reduce16(Bs);
            u32 cx = (u32)cr0 + (u32)cr1;
            u32 incl = cx, t;
            t = __shfl_up(incl, 1, 64); if (pr >= 1) incl += t;
            t = __shfl_up(incl, 2, 64); if (pr >= 2) incl += t;
            t = __shfl_up(incl, 4, 64); if (pr >= 4) incl += t;
            t = __shfl_up(incl, 8, 64); if (pr >= 8) incl += t;
            u32 excl = incl - cx;
            u32 tot  = __shfl(incl, 15, 64);
            u32 off = excl;                       // off[0] == 0 always
            if (cr0) { estream[off] = make_float4(sa0, sc0, w30, 0.f); off++; }
            if (cr1) { estream[off] = make_float4(sa1, sc1, w31, 0.f); }
            if (pr == 0) { accL[0] = make_float2(As, Bs); cntU[0] = tot; }

            float ra0 = sa0, rc0 = sc0, ra1 = sa1, rc1 = sc1;
            #pragma unroll
            for (int sg = 0; sg < 16; ++sg) {
                float* p = part[sg][pr];
                float t4 = p[4], t5 = p[5], t6 = p[6], t7 = p[7];
                p[0] = ra0; p[1] = rc0; p[2] = ra1; p[3] = rc1;
                ra0 += t4; rc0 += t5; ra1 += t6; rc1 += t7;
            }
        }
        __syncthreads();

        // ---- walk A: classify I=1..256, counts + AccP to LDS (no writes) ----
        {
            const float* p = part[seg][prl];
            float a0 = p[0], c0 = p[1], a1 = p[2], c1 = p[3];
            #pragma unroll 4
            for (int i = 0; i < 16; ++i) {
                int   j  = (seg << 4) + i;
                int   kj = pm[j];
                float w  = w1s[kj];
                float bb = b1s[kj];
                float2 v = vreg[i];
                float aw = fabsf(w);
                float cs = (w > 0.f) ? bb : -bb;
                a0 = fmaf(v.x, aw, a0); c0 = fmaf(v.x, cs, c0);
                a1 = fmaf(v.y, aw, a1); c1 = fmaf(v.y, cs, c1);

                float lo = kns[j];
                float hLo0 = fmaf(a0, lo, c0), hLo1 = fmaf(a1, lo, c1);
                float hHi0, hHi1;
                if (j < 255) {
                    float hi = kns[j + 1];
                    hHi0 = fmaf(a0, hi, c0); hHi1 = fmaf(a1, hi, c1);
                } else {
                    hHi0 = (a0 != 0.f) ? a0 : c0;
                    hHi1 = (a1 != 0.f) ? a1 : c1;
                }
                bool act0 = hLo0 > 0.f && hHi0 > 0.f, drp0 = hLo0 <= 0.f && hHi0 <= 0.f;
                bool act1 = hLo1 > 0.f && hHi1 > 0.f, drp1 = hLo1 <= 0.f && hHi1 <= 0.f;
                bool cr0 = !act0 && !drp0, cr1 = !act1 && !drp1;
                float As = (act0 ? w30 * a0 : 0.f) + (act1 ? w31 * a1 : 0.f);
                float Bs = (act0 ? w30 * c0 : 0.f) + (act1 ? w31 * c1 : 0.f);
                As = row_reduce16(As); Bs = row_reduce16(Bs);
                u32 cx = (u32)cr0 + (u32)cr1;
                u32 incl = cx, t;
                t = __shfl_up(incl, 1, 64); if (prl >= 1) incl += t;
                t = __shfl_up(incl, 2, 64); if (prl >= 2) incl += t;
                t = __shfl_up(incl, 4, 64); if (prl >= 4) incl += t;
                t = __shfl_up(incl, 8, 64); if (prl >= 8) incl += t;
                u32 tot  = __shfl(incl, (lane & ~15) + 15, 64);
                if (prl == 0) {
                    accL[j + 1] = make_float2(As, Bs);
                    cntU[j + 1] = tot;
                }
            }
        }
        __syncthreads();

        // ---- block scan: cntU[0..256] counts -> exclusive offsets; [257]=total
        if (tid < 64) {
            int base = tid << 2;
            u32 h0 = cntU[base], h1 = cntU[base + 1], h2 = cntU[base + 2], h3 = cntU[base + 3];
            u32 h4 = (tid == 63) ? cntU[256] : 0u;
            u32 lsum = h0 + h1 + h2 + h3 + h4;
            u32 run = lsum;
            #pragma unroll
            for (int off = 1; off < 64; off <<= 1) {
                u32 tt = __shfl_up(run, off, 64);
                if (lane >= off) run += tt;
            }
            u32 excl = run - lsum;
            cntU[base]     = excl;
            cntU[base + 1] = excl + h0;
            cntU[base + 2] = excl + h0 + h1;
            cntU[base + 3] = excl + h0 + h1 + h2;
            if (tid == 63) {
                cntU[256] = excl + h0 + h1 + h2 + h3;
                cntU[257] = excl + lsum;
            }
        }
        __syncthreads();

        // ---- coalesced write-out of AccP + offs ----
        for (int i = tid; i < 257; i += 256)
            AccP[(size_t)g * 257 + i] = accL[i];
        for (int i = tid; i < 258; i += 256)
            offs[(size_t)g * 258 + i] = (unsigned short)cntU[i];

        // ---- walk B: re-walk, write entries compacted at off[I]+excl ----
        {
            const float* p = part[seg][prl];
            float a0 = p[0], c0 = p[1], a1 = p[2], c1 = p[3];
            #pragma unroll 4
            for (int i = 0; i < 16; ++i) {
                int   j  = (seg << 4) + i;
                int   kj = pm[j];
                float w  = w1s[kj];
                float bb = b1s[kj];
                float2 v = vreg[i];
                float aw = fabsf(w);
                float cs = (w > 0.f) ? bb : -bb;
                a0 = fmaf(v.x, aw, a0); c0 = fmaf(v.x, cs, c0);
                a1 = fmaf(v.y, aw, a1); c1 = fmaf(v.y, cs, c1);

                float lo = kns[j];
                float hLo0 = fmaf(a0, lo, c0), hLo1 = fmaf(a1, lo, c1);
                float hHi0, hHi1;
                if (j < 255) {
                    float hi = kns[j + 1];
                    hHi0 = fmaf(a0, hi, c0); hHi1 = fmaf(a1, hi, c1);
                } else {
                    hHi0 = (a0 != 0.f) ? a0 : c0;
                    hHi1 = (a1 != 0.f) ? a1 : c1;
                }
                bool act0 = hLo0 > 0.f && hHi0 > 0.f, drp0 = hLo0 <= 0.f && hHi0 <= 0.f;
                bool act1 = hLo1 > 0.f && hHi1 > 0.f, drp1 = hLo1 <= 0.f && hHi1 <= 0.f;
                bool cr0 = !act0 && !drp0, cr1 = !act1 && !drp1;
                u32 cx = (u32)cr0 + (u32)cr1;
                u32 incl = cx, t;
                t = __shfl_up(incl, 1, 64); if (prl >= 1) incl += t;
                t = __shfl_up(incl, 2, 64); if (prl >= 2) incl += t;
                t = __shfl_up(incl, 4, 64); if (prl >= 4) incl += t;
                t = __shfl_up(incl, 8, 64); if (prl >= 8) incl += t;
                u32 excl = incl - cx;
                u32 off = cntU[j + 1] + excl;
                if (cr0) { estream[off] = make_float4(a0, c0, w30, 0.f); off++; }
                if (cr1) { estream[off] = make_float4(a1, c1, w31, 0.f); }
            }
        }
    } else {
        // ================= sort role: (node, quarter) =================
        const int t = blk - 512;
        const int n = t >> 2;
        const int q = t & 3;

        float* kn = w1s;                 // reuse LDS
        u32* hist = cntU;                // reuse LDS (257 <= 258)
        kn[tid] = knots[n * 256 + tid];
        hist[tid] = 0;
        if (tid == 0) hist[256] = 0;
        __syncthreads();

        const float* Sn = S + ((size_t)n << 13) + (q << 11);
        float sv[8]; int iv[8];
        #pragma unroll
        for (int j = 0; j < 8; ++j) {
            const float s = Sn[tid + (j << 8)];
            sv[j] = s;
            int I = 0;
            #pragma unroll
            for (int step = 128; step >= 1; step >>= 1)
                if (kn[I + step - 1] < s) I += step;
            if (I < 256 && kn[I] < s) I += 1;
            iv[j] = I;
            atomicAdd(&hist[I], 1u);
        }
        __syncthreads();

        if (tid < 64) {
            int base = tid << 2;
            u32 h0 = hist[base], h1 = hist[base + 1], h2 = hist[base + 2], h3 = hist[base + 3];
            u32 lsum = h0 + h1 + h2 + h3;
            u32 run = lsum;
            #pragma unroll
            for (int off = 1; off < 64; off <<= 1) {
                u32 tt = __shfl_up(run, off, 64);
                if (lane >= off) run += tt;
            }
            u32 excl = run - lsum;
            hist[base]     = excl;
            hist[base + 1] = excl + h0;
            hist[base + 2] = excl + h0 + h1;
            hist[base + 3] = excl + h0 + h1 + h2;
            if (tid == 63) hist[256] = excl + lsum;
        }
        __syncthreads();

        uint2* dst = sorted + ((size_t)n << 13) + (q << 11);
        #pragma unroll
        for (int j = 0; j < 8; ++j) {
            u32 pos = atomicAdd(&hist[iv[j]], 1u);
            u32 bglob = (u32)((q << 11) + tid + (j << 8));
            dst[pos] = make_uint2(__float_as_uint(sv[j]), ((u32)iv[j] << 13) | bglob);
        }
    }
}

// ---------------------------------------------------------------------------
// K3: evaluate z. Block = 256 consecutive SORTED samples of one node.
// grid (64, 32). z = A*s+B + sum over compact entries per strip.
// ---------------------------------------------------------------------------
__global__ __launch_bounds__(256) void eval_nodes(
    const uint2* __restrict__ sorted, const float4* __restrict__ entries,
    const float2* __restrict__ AccP, const unsigned short* __restrict__ offs,
    const float* __restrict__ b3, float* __restrict__ Z)
{
    const int n   = blockIdx.x;
    const int c0  = blockIdx.y << 8;
    const int tid = threadIdx.x;

    const uint2 ent = sorted[((size_t)n << 13) + c0 + tid];
    const float s   = __uint_as_float(ent.x);
    const int   I   = (int)(ent.y >> 13);
    const int   bl  = (int)(ent.y & 8191u);

    float A = 0.f, B = 0.f, zc = 0.f;
    #pragma unroll
    for (int st = 0; st < 8; ++st) {
        const int g = (n << 3) + st;
        float2 ap = AccP[(size_t)g * 257 + I];
        A += ap.x; B += ap.y;
        const unsigned short* op = offs + (size_t)g * 258 + I;
        u32 o0 = op[0], o1 = op[1];
        const float4* ep = entries + (size_t)g * CAP;
        for (u32 jj = o0; jj < o1; ++jj) {
            float4 e = ep[jj];
            zc = fmaf(e.z, fmaxf(fmaf(e.x, s, e.y), 0.f), zc);
        }
    }
    Z[((size_t)n << 13) + bl] = fmaf(A, s, B) + zc + b3[n];
}

// ---------------------------------------------------------------------------
// K4: 65-way softmax, Z read via 64x64 LDS transpose (coalesced).
// ---------------------------------------------------------------------------
__global__ __launch_bounds__(256) void softmax_rows(
    const float* __restrict__ Q, const float* __restrict__ Y,
    const float* __restrict__ Z, const float* __restrict__ bias0,
    float* __restrict__ out)
{
    __shared__ float ts[64][65];
    const int b0   = blockIdx.x << 6;
    const int tid  = threadIdx.x;
    const int lane = tid & 63;
    const int wv   = tid >> 6;

    #pragma unroll
    for (int jj = 0; jj < 16; jj++) {
        int idx = tid + (jj << 8);
        int nn = idx >> 6, bb = idx & 63;
        ts[bb][nn] = Z[((size_t)nn << 13) + b0 + bb];
    }
    __syncthreads();

    const float bias = bias0[0];
    #pragma unroll 2
    for (int r = 0; r < 16; ++r) {
        const int row = (wv << 4) + r;
        const int b   = b0 + row;

        float s = Q[(size_t)b * 64 + lane] * Y[(size_t)b * 64 + lane];
        float ssum = s;
        #pragma unroll
        for (int mask = 32; mask >= 1; mask >>= 1) ssum += __shfl_xor(ssum, mask, 64);
        const float z0 = bias - ssum;

        float zl = ts[row][lane];
        float mx = zl;
        #pragma unroll
        for (int mask = 32; mask >= 1; mask >>= 1) mx = fmaxf(mx, __shfl_xor(mx, mask, 64));
        mx = fmaxf(mx, z0);

        float el = expf(zl - mx);
        float e0 = expf(z0 - mx);
        float den = el;
        #pragma unroll
        for (int mask = 32; mask >= 1; mask >>= 1) den += __shfl_xor(den, mask, 64);
        den += e0;
        const float inv = 1.0f / den;

        out[(size_t)b * 65 + 1 + lane] = el * inv;
        if (lane == 0) out[(size_t)b * 65] = e0 * inv;
    }
}

// ---------------------------------------------------------------------------
extern "C" void kernel_launch(void* const* d_in, const int* in_sizes, int n_in,
                              void* d_out, int out_size, void* d_ws, size_t ws_size,
                              hipStream_t stream)
{
    const float* Q     = (const float*)d_in[0];
    const float* Y     = (const float*)d_in[1];
    const float* W1    = (const float*)d_in[2];
    const float* b1    = (const float*)d_in[3];
    const float* W2    = (const float*)d_in[4];
    const float* b2    = (const float*)d_in[5];
    const float* W3    = (const float*)d_in[6];
    const float* b3    = (const float*)d_in[7];
    const float* bias0 = (const float*)d_in[8];
    float* out = (float*)d_out;

    // ws layout (bytes):
    // [0        ) entries 64*8*8224*16 = 67,371,008
    // [67371008 ) AccP    64*8*257*8   =  1,052,672
    // [68423680 ) offs    64*8*258*2   =    264,192
    // [68687872 ) S       2,097,152
    // [70785024 ) Z       2,097,152
    // [72882176 ) knots   65,536
    // [72947712 ) perm    65,536
    // [73013248 ) sorted  4,194,304    total 77,207,552
    char* ws = (char*)d_ws;
    float4* entries       = (float4*)ws;
    float2* AccP          = (float2*)(ws + 67371008);
    unsigned short* offs  = (unsigned short*)(ws + 68423680);
    float* S              = (float*)(ws + 68687872);
    float* Z              = (float*)(ws + 70785024);
    float* knots          = (float*)(ws + 72882176);
    int*   perm           = (int*)  (ws + 72947712);
    uint2* sorted         = (uint2*)(ws + 73013248);

    prep<<<192, 256, 0, stream>>>(Q, Y, W1, b1, S, knots, perm);
    build_sort<<<768, 256, 0, stream>>>(W1, b1, W2, b2, W3, perm, S, knots,
                                        entries, AccP, offs, sorted);
    eval_nodes<<<dim3(64, 32), 256, 0, stream>>>(sorted, entries, AccP, offs, b3, Z);
    softmax_rows<<<128, 256, 0, stream>>>(Q, Y, Z, bias0, out);
}

// Round 22
// 55.714 us; speedup vs baseline: 1.1200x; 1.1200x over previous
//
#include <hip/hip_runtime.h>
#include <hip/hip_bf16.h>

// B=8192 rows, N=64 nodes, C=256. Per node: MLP 1->C->C->1 on s=Q*Y, then
// softmax over [z0, z_1..z_64]. Output f32 [B, 65].
//
// Round 22: R20 (proven 55.0us, single-walk exact compaction) + ONE change:
//  - AccP/cnt staged in LDS during the walk, written out strip-major and
//    coalesced afterwards (R20 wrote them scattered at partial-line
//    granularity from inside the walk). Entries unchanged (R20 layout).

typedef unsigned int u32;

// sum across each 16-lane DPP row; every lane gets the row total
__device__ __forceinline__ float row_reduce16(float x) {
    int v;
    v = __builtin_amdgcn_update_dpp(0, __float_as_int(x), 0xB1, 0xF, 0xF, false);
    x += __int_as_float(v);
    v = __builtin_amdgcn_update_dpp(0, __float_as_int(x), 0x4E, 0xF, 0xF, false);
    x += __int_as_float(v);
    v = __builtin_amdgcn_update_dpp(0, __float_as_int(x), 0x124, 0xF, 0xF, false);
    x += __int_as_float(v);
    v = __builtin_amdgcn_update_dpp(0, __float_as_int(x), 0x128, 0xF, 0xF, false);
    x += __int_as_float(v);
    return x;
}

// ---------------------------------------------------------------------------
// K1: prep. blocks 0..127: S[n][b] = Q[b][n]*Y[b][n] (64x64 LDS transpose).
//           blocks 128..191: knee s*_k = -b1_k/w1_k + bitonic sort.
// ---------------------------------------------------------------------------
__global__ __launch_bounds__(256) void prep(
    const float* __restrict__ Q, const float* __restrict__ Y,
    const float* __restrict__ W1, const float* __restrict__ b1,
    float* __restrict__ S, float* __restrict__ knots, int* __restrict__ perm)
{
    __shared__ float ts[64][65];
    __shared__ float key[256];
    __shared__ int   idx[256];

    const int blk = blockIdx.x;
    const int tid = threadIdx.x;

    if (blk < 128) {
        const int b0 = blk << 6;
        #pragma unroll
        for (int jj = 0; jj < 16; jj++) {
            int i = tid + (jj << 8);
            int r = i >> 6, c = i & 63;
            ts[r][c] = Q[(size_t)(b0 + r) * 64 + c] * Y[(size_t)(b0 + r) * 64 + c];
        }
        __syncthreads();
        #pragma unroll
        for (int jj = 0; jj < 16; jj++) {
            int i = tid + (jj << 8);
            int nn = i >> 6, bb = i & 63;
            S[((size_t)nn << 13) + b0 + bb] = ts[bb][nn];
        }
    } else {
        const int n = blk - 128;
        {
            float w = W1[n * 256 + tid];
            float b = b1[n * 256 + tid];
            key[tid] = -b / w;
            idx[tid] = tid;
        }
        __syncthreads();
        for (int k = 2; k <= 256; k <<= 1) {
            for (int j = k >> 1; j > 0; j >>= 1) {
                int p = tid ^ j;
                if (p > tid) {
                    float a = key[tid], c = key[p];
                    bool up = ((tid & k) == 0);
                    if (up ? (a > c) : (a < c)) {
                        int ia = idx[tid];
                        key[tid] = c; idx[tid] = idx[p];
                        key[p] = a; idx[p] = ia;
                    }
                }
                __syncthreads();
            }
        }
        knots[n * 256 + tid] = key[tid];
        perm[n * 256 + tid]  = idx[tid];
    }
}

// ---------------------------------------------------------------------------
// K2: build_sort.
// blocks 0..511: scan + classify; (n = blk>>3, strip = blk&7), 256 thr =
//   (seg 0..15) x (pair 0..15). AccP/cnt staged in LDS -> coalesced
//   strip-major writeout. entries[(n*257+I)*8+strip][<=32] scattered (R20).
// blocks 512..767: sort one (node, quarter) of samples by interval.
// ---------------------------------------------------------------------------
__global__ __launch_bounds__(256) void build_sort(
    const float* __restrict__ W1, const float* __restrict__ b1,
    const float* __restrict__ W2, const float* __restrict__ b2,
    const float* __restrict__ W3, const int* __restrict__ perm,
    const float* __restrict__ S, const float* __restrict__ knots,
    float4* __restrict__ entries, float2* __restrict__ AccP,
    unsigned char* __restrict__ cnt8, uint2* __restrict__ sorted)
{
    __shared__ float  w1s[256], b1s[256], kns[256];
    __shared__ int    pm[256];
    __shared__ float  part[16][16][8];
    __shared__ float2 accL[257];
    __shared__ u32    hist[257];      // sort role: histogram; scan role: cntL

    const int blk = blockIdx.x;
    const int tid = threadIdx.x;
    const int lane = tid & 63;

    if (blk < 512) {
        // ================= scan+classify role =================
        const int n    = blk >> 3;
        const int strip= blk & 7;
        const int prl  = tid & 15;
        const int seg  = tid >> 4;
        const int prg  = (strip << 4) + prl;
        const int d0   = prg << 1;
        const int g    = (n << 3) + strip;     // strip-major group id

        w1s[tid] = W1[n * 256 + tid];
        b1s[tid] = b1[n * 256 + tid];
        kns[tid] = knots[n * 256 + tid];
        pm[tid]  = perm[n * 256 + tid];
        __syncthreads();

        const float w30 = W3[n * 256 + d0];
        const float w31 = W3[n * 256 + d0 + 1];
        const float* W2n = W2 + ((size_t)n << 16);
        float2 vreg[16];                 // phase-1 W2 cache, reused in phase 3

        // phase 1: per-segment partials (cache W2 loads in regs)
        {
            float ba0 = 0.f, bc0 = 0.f, ba1 = 0.f, bc1 = 0.f;
            float da0 = 0.f, dc0 = 0.f, da1 = 0.f, dc1 = 0.f;
            #pragma unroll
            for (int i = 0; i < 16; ++i) {
                int   kj = pm[(seg << 4) + i];
                float w  = w1s[kj];
                float bb = b1s[kj];
                float2 v = *reinterpret_cast<const float2*>(&W2n[kj * 256 + d0]);
                vreg[i] = v;
                if (w < 0.f) {
                    ba0 = fmaf(v.x, w, ba0); bc0 = fmaf(v.x, bb, bc0);
                    ba1 = fmaf(v.y, w, ba1); bc1 = fmaf(v.y, bb, bc1);
                }
                float aw = fabsf(w);
                float cs = (w > 0.f) ? bb : -bb;
                da0 = fmaf(v.x, aw, da0); dc0 = fmaf(v.x, cs, dc0);
                da1 = fmaf(v.y, aw, da1); dc1 = fmaf(v.y, cs, dc1);
            }
            float* p = part[seg][prl];
            p[0] = ba0; p[1] = bc0; p[2] = ba1; p[3] = bc1;
            p[4] = da0; p[5] = dc0; p[6] = da1; p[7] = dc1;
        }
        __syncthreads();

        // phase 2 (16 threads): base totals, classify I=0, seed segments
        if (tid < 16) {
            const int pr = tid;
            float sa0 = 0.f, sc0 = 0.f, sa1 = 0.f, sc1 = 0.f;
            #pragma unroll
            for (int sg = 0; sg < 16; ++sg) {
                const float* p = part[sg][pr];
                sa0 += p[0]; sc0 += p[1]; sa1 += p[2]; sc1 += p[3];
            }
            const int dd = ((strip << 4) + pr) << 1;
            sc0 += b2[n * 256 + dd];
            sc1 += b2[n * 256 + dd + 1];

            float k0 = kns[0];
            float hLo0 = (sa0 != 0.f) ? -sa0 : sc0;
            float hHi0 = fmaf(sa0, k0, sc0);
            float hLo1 = (sa1 != 0.f) ? -sa1 : sc1;
            float hHi1 = fmaf(sa1, k0, sc1);
            bool act0 = hLo0 > 0.f && hHi0 > 0.f, drp0 = hLo0 <= 0.f && hHi0 <= 0.f;
            bool act1 = hLo1 > 0.f && hHi1 > 0.f, drp1 = hLo1 <= 0.f && hHi1 <= 0.f;
            bool cr0 = !act0 && !drp0, cr1 = !act1 && !drp1;
            float As = (act0 ? w30 * sa0 : 0.f) + (act1 ? w31 * sa1 : 0.f);
            float Bs = (act0 ? w30 * sc0 : 0.f) + (act1 ? w31 * sc1 : 0.f);
            As = row_reduce16(As); Bs = row_reduce16(Bs);
            u32 cx = (u32)cr0 + (u32)cr1;
            u32 incl = cx, t;
            t = __shfl_up(incl, 1, 64); if (pr >= 1) incl += t;
            t = __shfl_up(incl, 2, 64); if (pr >= 2) incl += t;
            t = __shfl_up(incl, 4, 64); if (pr >= 4) incl += t;
            t = __shfl_up(incl, 8, 64); if (pr >= 8) incl += t;
            u32 excl = incl - cx;
            u32 tot  = __shfl(incl, 15, 64);
            size_t eb = ((size_t)(n * 257 + 0) * 8 + strip) * 32;
            u32 off = excl;
            if (cr0) { entries[eb + off] = make_float4(sa0, sc0, w30, 0.f); off++; }
            if (cr1) { entries[eb + off] = make_float4(sa1, sc1, w31, 0.f); }
            if (pr == 0) { accL[0] = make_float2(As, Bs); hist[0] = tot; }

            float ra0 = sa0, rc0 = sc0, ra1 = sa1, rc1 = sc1;
            #pragma unroll
            for (int sg = 0; sg < 16; ++sg) {
                float* p = part[sg][pr];
                float t4 = p[4], t5 = p[5], t6 = p[6], t7 = p[7];
                p[0] = ra0; p[1] = rc0; p[2] = ra1; p[3] = rc1;
                ra0 += t4; rc0 += t5; ra1 += t6; rc1 += t7;
            }
        }
        __syncthreads();

        // phase 3: re-walk segment; classify I=j+1, emit entries, stage Acc/cnt
        {
            const float* p = part[seg][prl];
            float a0 = p[0], c0 = p[1], a1 = p[2], c1 = p[3];
            #pragma unroll 4
            for (int i = 0; i < 16; ++i) {
                int   j  = (seg << 4) + i;
                int   kj = pm[j];
                float w  = w1s[kj];
                float bb = b1s[kj];
                float2 v = vreg[i];
                float aw = fabsf(w);
                float cs = (w > 0.f) ? bb : -bb;
                a0 = fmaf(v.x, aw, a0); c0 = fmaf(v.x, cs, c0);
                a1 = fmaf(v.y, aw, a1); c1 = fmaf(v.y, cs, c1);

                float lo = kns[j];
                float hLo0 = fmaf(a0, lo, c0), hLo1 = fmaf(a1, lo, c1);
                float hHi0, hHi1;
                if (j < 255) {
                    float hi = kns[j + 1];
                    hHi0 = fmaf(a0, hi, c0); hHi1 = fmaf(a1, hi, c1);
                } else {
                    hHi0 = (a0 != 0.f) ? a0 : c0;
                    hHi1 = (a1 != 0.f) ? a1 : c1;
                }
                bool act0 = hLo0 > 0.f && hHi0 > 0.f, drp0 = hLo0 <= 0.f && hHi0 <= 0.f;
                bool act1 = hLo1 > 0.f && hHi1 > 0.f, drp1 = hLo1 <= 0.f && hHi1 <= 0.f;
                bool cr0 = !act0 && !drp0, cr1 = !act1 && !drp1;
                float As = (act0 ? w30 * a0 : 0.f) + (act1 ? w31 * a1 : 0.f);
                float Bs = (act0 ? w30 * c0 : 0.f) + (act1 ? w31 * c1 : 0.f);
                As = row_reduce16(As); Bs = row_reduce16(Bs);
                u32 cx = (u32)cr0 + (u32)cr1;
                u32 incl = cx, t;
                t = __shfl_up(incl, 1, 64); if (prl >= 1) incl += t;
                t = __shfl_up(incl, 2, 64); if (prl >= 2) incl += t;
                t = __shfl_up(incl, 4, 64); if (prl >= 4) incl += t;
                t = __shfl_up(incl, 8, 64); if (prl >= 8) incl += t;
                u32 excl = incl - cx;
                u32 tot  = __shfl(incl, (lane & ~15) + 15, 64);
                size_t eb = ((size_t)(n * 257 + (j + 1)) * 8 + strip) * 32;
                u32 off = excl;
                if (cr0) { entries[eb + off] = make_float4(a0, c0, w30, 0.f); off++; }
                if (cr1) { entries[eb + off] = make_float4(a1, c1, w31, 0.f); }
                if (prl == 0) {
                    accL[j + 1] = make_float2(As, Bs);
                    hist[j + 1] = tot;
                }
            }
        }
        __syncthreads();

        // coalesced strip-major writeout of AccP + cnt
        for (int i = tid; i < 257; i += 256) {
            AccP[(size_t)g * 257 + i] = accL[i];
            cnt8[(size_t)g * 257 + i] = (unsigned char)hist[i];
        }
    } else {
        // ================= sort role: (node, quarter) =================
        const int t = blk - 512;
        const int n = t >> 2;
        const int q = t & 3;

        float* kn = w1s;                 // reuse LDS
        kn[tid] = knots[n * 256 + tid];
        hist[tid] = 0;
        if (tid == 0) hist[256] = 0;
        __syncthreads();

        const float* Sn = S + ((size_t)n << 13) + (q << 11);
        float sv[8]; int iv[8];
        #pragma unroll
        for (int j = 0; j < 8; ++j) {
            const float s = Sn[tid + (j << 8)];
            sv[j] = s;
            int I = 0;
            #pragma unroll
            for (int step = 128; step >= 1; step >>= 1)
                if (kn[I + step - 1] < s) I += step;
            if (I < 256 && kn[I] < s) I += 1;
            iv[j] = I;
            atomicAdd(&hist[I], 1u);
        }
        __syncthreads();

        if (tid < 64) {
            int base = tid << 2;
            u32 h0 = hist[base], h1 = hist[base + 1], h2 = hist[base + 2], h3 = hist[base + 3];
            u32 lsum = h0 + h1 + h2 + h3;
            u32 run = lsum;
            #pragma unroll
            for (int off = 1; off < 64; off <<= 1) {
                u32 tt = __shfl_up(run, off, 64);
                if (lane >= off) run += tt;
            }
            u32 excl = run - lsum;
            hist[base]     = excl;
            hist[base + 1] = excl + h0;
            hist[base + 2] = excl + h0 + h1;
            hist[base + 3] = excl + h0 + h1 + h2;
            if (tid == 63) hist[256] = excl + lsum;
        }
        __syncthreads();

        uint2* dst = sorted + ((size_t)n << 13) + (q << 11);
        #pragma unroll
        for (int j = 0; j < 8; ++j) {
            u32 pos = atomicAdd(&hist[iv[j]], 1u);
            u32 bglob = (u32)((q << 11) + tid + (j << 8));
            dst[pos] = make_uint2(__float_as_uint(sv[j]), ((u32)iv[j] << 13) | bglob);
        }
    }
}

// ---------------------------------------------------------------------------
// K3: evaluate z. Block = 256 consecutive SORTED samples of one node.
// grid (64, 32). z = A*s+B + sum over crossing entries.
// ---------------------------------------------------------------------------
__global__ __launch_bounds__(256) void eval_nodes(
    const uint2* __restrict__ sorted, const float4* __restrict__ entries,
    const float2* __restrict__ AccP, const unsigned char* __restrict__ cnt8,
    const float* __restrict__ b3, float* __restrict__ Z)
{
    const int n   = blockIdx.x;
    const int c0  = blockIdx.y << 8;
    const int tid = threadIdx.x;

    const uint2 ent = sorted[((size_t)n << 13) + c0 + tid];
    const float s   = __uint_as_float(ent.x);
    const int   I   = (int)(ent.y >> 13);
    const int   bl  = (int)(ent.y & 8191u);

    const size_t ibase = (size_t)(n * 257 + I) * 8;

    float A = 0.f, B = 0.f, zc = 0.f;
    #pragma unroll
    for (int st = 0; st < 8; ++st) {
        const size_t gi = (size_t)((n << 3) + st) * 257 + I;
        float2 ap = AccP[gi];
        A += ap.x; B += ap.y;
        u32 c = cnt8[gi];
        const float4* ep = entries + ((ibase + st) << 5);
        for (u32 jj = 0; jj < c; ++jj) {
            float4 e = ep[jj];
            zc = fmaf(e.z, fmaxf(fmaf(e.x, s, e.y), 0.f), zc);
        }
    }
    Z[((size_t)n << 13) + bl] = fmaf(A, s, B) + zc + b3[n];
}

// ---------------------------------------------------------------------------
// K4: 65-way softmax, Z read via 64x64 LDS transpose (coalesced).
// ---------------------------------------------------------------------------
__global__ __launch_bounds__(256) void softmax_rows(
    const float* __restrict__ Q, const float* __restrict__ Y,
    const float* __restrict__ Z, const float* __restrict__ bias0,
    float* __restrict__ out)
{
    __shared__ float ts[64][65];
    const int b0   = blockIdx.x << 6;
    const int tid  = threadIdx.x;
    const int lane = tid & 63;
    const int wv   = tid >> 6;

    #pragma unroll
    for (int jj = 0; jj < 16; jj++) {
        int idx = tid + (jj << 8);
        int nn = idx >> 6, bb = idx & 63;
        ts[bb][nn] = Z[((size_t)nn << 13) + b0 + bb];
    }
    __syncthreads();

    const float bias = bias0[0];
    #pragma unroll 2
    for (int r = 0; r < 16; ++r) {
        const int row = (wv << 4) + r;
        const int b   = b0 + row;

        float s = Q[(size_t)b * 64 + lane] * Y[(size_t)b * 64 + lane];
        float ssum = s;
        #pragma unroll
        for (int mask = 32; mask >= 1; mask >>= 1) ssum += __shfl_xor(ssum, mask, 64);
        const float z0 = bias - ssum;

        float zl = ts[row][lane];
        float mx = zl;
        #pragma unroll
        for (int mask = 32; mask >= 1; mask >>= 1) mx = fmaxf(mx, __shfl_xor(mx, mask, 64));
        mx = fmaxf(mx, z0);

        float el = expf(zl - mx);
        float e0 = expf(z0 - mx);
        float den = el;
        #pragma unroll
        for (int mask = 32; mask >= 1; mask >>= 1) den += __shfl_xor(den, mask, 64);
        den += e0;
        const float inv = 1.0f / den;

        out[(size_t)b * 65 + 1 + lane] = el * inv;
        if (lane == 0) out[(size_t)b * 65] = e0 * inv;
    }
}

// ---------------------------------------------------------------------------
extern "C" void kernel_launch(void* const* d_in, const int* in_sizes, int n_in,
                              void* d_out, int out_size, void* d_ws, size_t ws_size,
                              hipStream_t stream)
{
    const float* Q     = (const float*)d_in[0];
    const float* Y     = (const float*)d_in[1];
    const float* W1    = (const float*)d_in[2];
    const float* b1    = (const float*)d_in[3];
    const float* W2    = (const float*)d_in[4];
    const float* b2    = (const float*)d_in[5];
    const float* W3    = (const float*)d_in[6];
    const float* b3    = (const float*)d_in[7];
    const float* bias0 = (const float*)d_in[8];
    float* out = (float*)d_out;

    // ws layout (bytes):
    // [0        ) entries 64*257*8*32*16 = 67,371,008
    // [67371008 ) AccP    64*8*257*8    =  1,052,672
    // [68423680 ) cnt8    64*8*257      =    131,584
    // [68555264 ) S       2,097,152
    // [70652416 ) Z       2,097,152
    // [72749568 ) knots   65,536
    // [72815104 ) perm    65,536
    // [72880640 ) sorted  4,194,304     total 77,074,944
    char* ws = (char*)d_ws;
    float4* entries      = (float4*)ws;
    float2* AccP         = (float2*)(ws + 67371008);
    unsigned char* cnt8  = (unsigned char*)(ws + 68423680);
    float* S             = (float*)(ws + 68555264);
    float* Z             = (float*)(ws + 70652416);
    float* knots         = (float*)(ws + 72749568);
    int*   perm          = (int*)  (ws + 72815104);
    uint2* sorted        = (uint2*)(ws + 72880640);

    prep<<<192, 256, 0, stream>>>(Q, Y, W1, b1, S, knots, perm);
    build_sort<<<768, 256, 0, stream>>>(W1, b1, W2, b2, W3, perm, S, knots,
                                        entries, AccP, cnt8, sorted);
    eval_nodes<<<dim3(64, 32), 256, 0, stream>>>(sorted, entries, AccP, cnt8, b3, Z);
    softmax_rows<<<128, 256, 0, stream>>>(Q, Y, Z, bias0, out);
}